// Round 21
// baseline (113.197 us; speedup 1.0000x reference)
//
#include <hip/hip_runtime.h>
#include <cstdint>
#include <cstddef>

#define NN  768
#define IND 64
#define HD  128
#define EFD 16
#define TT  3

typedef __attribute__((ext_vector_type(8)))  short short8;
typedef __attribute__((ext_vector_type(16))) float floatx16;

__device__ __forceinline__ unsigned f2bf(float f){
    unsigned u = __float_as_uint(f);
    return (u + 0x7FFFu + ((u >> 16) & 1u)) >> 16;
}
// monotonic uint encoding of float for atomicMax
__device__ __forceinline__ unsigned enc_f(float f){
    unsigned b = __float_as_uint(f);
    return (b & 0x80000000u) ? ~b : (b | 0x80000000u);
}
__device__ __forceinline__ float dec_f(unsigned e){
    return __uint_as_float((e & 0x80000000u) ? (e & 0x7FFFFFFFu) : ~e);
}
#define ENC_NEG_INF 0x007FFFFFu

// ---------- K1: z(0)+zsrc/zdst(0) row-local; u_enc init; output init (NO conv pass) ----------
__global__ __launch_bounds__(256)
void k1_ker(const float* __restrict__ states,
            const float* __restrict__ We, const float* __restrict__ be,
            const float* __restrict__ Wm, float* __restrict__ out,
            float* __restrict__ z, float* __restrict__ zsrc, float* __restrict__ zdst,
            unsigned* __restrict__ u_enc)
{
    int bid = blockIdx.x, tid = threadIdx.x;
    __shared__ float sZ[HD];
    if (tid < HD){
        float acc = be[tid];
        const float* srow = states + bid * IND;
        #pragma unroll
        for (int k = 0; k < IND; ++k) acc += srow[k] * We[k * HD + tid];
        z[bid * HD + tid] = acc;
        sZ[tid] = acc;
    }
    __syncthreads();
    {
        int h = tid & 127, which = tid >> 7;
        const float* W = Wm + which * HD * HD;
        float acc = 0.f;
        #pragma unroll 8
        for (int k = 0; k < HD; ++k) acc += sZ[k] * W[k * HD + h];
        (which ? zdst : zsrc)[bid * HD + h] = acc;
    }
    int gid0 = bid * 256 + tid;
    // u_enc init: 3*768*128 = 294912 over 196608 threads
    u_enc[gid0] = ENC_NEG_INF;
    if (gid0 < 98304) u_enc[196608 + gid0] = ENC_NEG_INF;
    if (gid0 < NN * IND){ int n = gid0 >> 6, c = gid0 & 63; out[n * 256 + c] = states[n * IND + c]; }
    if (gid0 < NN * 2){ int n = gid0 >> 1, cc = gid0 & 1; out[196608 + n * 8 + cc] = 0.f; }
}

// ---------- K2 v4: MFMA msgmax, f32 edges converted on the fly, 4 h-tiles/wave, LDS reduce ----------
// main blocks: (jt 0..23) x (ch 0..15) = 384 ; aux blocks 384..511: msbuf zero + stop(t-1)
__global__ __launch_bounds__(256)
void k2_ker(const float* __restrict__ edges, const float* __restrict__ zsrc,
            const float* __restrict__ Wm, unsigned* __restrict__ u_enc,
            const float* __restrict__ hid, unsigned long long* __restrict__ msbuf,
            const float* __restrict__ Wt, const float* __restrict__ bt,
            float* __restrict__ out, int t)
{
    int bid = blockIdx.x, tid = threadIdx.x;
    if (bid < 384){
        __shared__ float sm[4][4096];      // 64 KB: [wave][ht*1024 + row*32 + col]
        const float* WmE = Wm + 2 * HD * HD;
        int lane = tid & 63;
        int wv = tid >> 6;
        int jt = bid % 24, ch = bid / 24;  // ch 0..15
        int j0 = jt * 32;
        int i0 = ch * 48 + wv * 12;        // 16 chunks x 4 waves x 12 i = 768
        int ln = lane & 31, lh = lane >> 5;

        short8 b[4];
        #pragma unroll
        for (int ht = 0; ht < 4; ++ht)
            #pragma unroll
            for (int q = 0; q < 8; ++q)
                b[ht][q] = (short)f2bf(WmE[(8 * lh + q) * HD + ht * 32 + ln]);

        floatx16 czero;
        floatx16 run[4];
        #pragma unroll
        for (int r = 0; r < 16; ++r) czero[r] = 0.f;
        #pragma unroll
        for (int ht = 0; ht < 4; ++ht)
            #pragma unroll
            for (int r = 0; r < 16; ++r) run[ht][r] = -INFINITY;

        const float* abase = edges + (size_t)(j0 + ln) * EFD + 8 * lh;
        for (int ii = 0; ii < 12; ++ii){
            int i = i0 + ii;
            const float* ap = abase + (size_t)i * NN * EFD;
            float4 e0 = *reinterpret_cast<const float4*>(ap);
            float4 e1 = *reinterpret_cast<const float4*>(ap + 4);
            short8 a;
            a[0] = (short)f2bf(e0.x); a[1] = (short)f2bf(e0.y);
            a[2] = (short)f2bf(e0.z); a[3] = (short)f2bf(e0.w);
            a[4] = (short)f2bf(e1.x); a[5] = (short)f2bf(e1.y);
            a[6] = (short)f2bf(e1.z); a[7] = (short)f2bf(e1.w);
            const float* zr = zsrc + i * HD + ln;
            float zs0 = zr[0], zs1 = zr[32], zs2 = zr[64], zs3 = zr[96];
            floatx16 d0 = __builtin_amdgcn_mfma_f32_32x32x16_bf16(a, b[0], czero, 0, 0, 0);
            #pragma unroll
            for (int r = 0; r < 16; ++r) run[0][r] = fmaxf(run[0][r], d0[r] + zs0);
            floatx16 d1 = __builtin_amdgcn_mfma_f32_32x32x16_bf16(a, b[1], czero, 0, 0, 0);
            #pragma unroll
            for (int r = 0; r < 16; ++r) run[1][r] = fmaxf(run[1][r], d1[r] + zs1);
            floatx16 d2 = __builtin_amdgcn_mfma_f32_32x32x16_bf16(a, b[2], czero, 0, 0, 0);
            #pragma unroll
            for (int r = 0; r < 16; ++r) run[2][r] = fmaxf(run[2][r], d2[r] + zs2);
            floatx16 d3 = __builtin_amdgcn_mfma_f32_32x32x16_bf16(a, b[3], czero, 0, 0, 0);
            #pragma unroll
            for (int r = 0; r < 16; ++r) run[3][r] = fmaxf(run[3][r], d3[r] + zs3);
        }
        // per-wave maxes -> LDS
        #pragma unroll
        for (int ht = 0; ht < 4; ++ht)
            #pragma unroll
            for (int r = 0; r < 16; ++r){
                int row = (r & 3) + 8 * (r >> 2) + 4 * lh;
                sm[wv][ht * 1024 + row * 32 + ln] = run[ht][r];
            }
        __syncthreads();
        // 4-wave reduce + single atomic per element per block
        unsigned* ub = u_enc + t * (NN * HD);
        #pragma unroll
        for (int e = tid; e < 4096; e += 256){
            float m = fmaxf(fmaxf(sm[0][e], sm[1][e]), fmaxf(sm[2][e], sm[3][e]));
            int ht = e >> 10, rr = e & 1023;
            int jr = rr >> 5, hc = rr & 31;
            atomicMax(&ub[(j0 + jr) * HD + ht * 32 + hc], enc_f(m));
        }
    } else {
        int b2 = bid - 384;
        if (b2 == 0 && tid < HD) msbuf[(t & 1) * HD + tid] = 0ull;
        if (t > 0 && tid < 12){
            int row = b2 * 6 + (tid >> 1), cc = tid & 1;
            float a2 = bt[cc];
            const float* hrow = hid + row * HD;
            #pragma unroll 8
            for (int k = 0; k < HD; ++k) a2 += hrow[k] * Wt[k * 2 + cc];
            const unsigned long long* msp = msbuf + ((t - 1) & 1) * HD;
            const float sc = 1.0f / (768.0f * 1048576.0f);
            #pragma unroll 8
            for (int k = 0; k < HD; ++k){
                float mk = (float)(long long)msp[k] * sc;
                a2 += mk * Wt[(HD + k) * 2 + cc];
            }
            out[196608 + row * 8 + t * 2 + cc] = 1.f / (1.f + expf(-a2));
        }
    }
}

// ---------- K3 v5: 6 rows/block, 128 blocks, 512 threads; weight float4 loaded once, reused x6 rows ----------
__global__ __launch_bounds__(512)
void k3_ker(float* __restrict__ z, float* __restrict__ zsrc, float* __restrict__ zdst,
            const unsigned* __restrict__ u_enc, const float* __restrict__ bm,
            const float* __restrict__ Wu, const float* __restrict__ bu,
            const float* __restrict__ Wd, const float* __restrict__ bd,
            const float* __restrict__ We, const float* __restrict__ be,
            const float* __restrict__ Wm,
            float* __restrict__ hid, float* __restrict__ state,
            unsigned long long* __restrict__ msbuf, float* __restrict__ out, int t)
{
    __shared__ float sA[6][256];
    __shared__ float sB[6][256];
    __shared__ float sC[6][192];
    __shared__ float sH[6][128];
    __shared__ float sZ2[6][128];
    __shared__ float pp[16][6][128];

    int tid = threadIdx.x;
    int m0 = blockIdx.x * 6;

    const float4* Wu4  = reinterpret_cast<const float4*>(Wu);
    const float4* Wd4  = reinterpret_cast<const float4*>(Wd);
    const float4* We4  = reinterpret_cast<const float4*>(We);
    const float4* WmS4 = reinterpret_cast<const float4*>(Wm);
    const float4* WmD4 = reinterpret_cast<const float4*>(Wm + HD * HD);
    float* ppf = &pp[0][0][0];

    for (int i = tid; i < 1536; i += 512){
        int r = i >> 8, k = i & 255;
        float v;
        if (k < HD) v = z[(m0 + r) * HD + k];
        else {
            int kk = k - HD;
            v = dec_f(u_enc[t * (NN * HD) + (m0 + r) * HD + kk]) + zdst[(m0 + r) * HD + kk] + bm[kk];
        }
        sA[r][k] = v;
    }
    __syncthreads();

    int h4 = tid & 31, ksl = tid >> 5;
    int c4 = tid & 15, ksl2 = tid >> 4;

    {
        float4 a0 = make_float4(0,0,0,0), a1 = a0, a2 = a0, a3 = a0, a4 = a0, a5 = a0;
        #pragma unroll
        for (int kk = 0; kk < 16; ++kk){
            int k = ksl * 16 + kk;
            float4 w = Wu4[k * 32 + h4];
            float s0 = sA[0][k], s1 = sA[1][k], s2 = sA[2][k];
            float s3 = sA[3][k], s4 = sA[4][k], s5 = sA[5][k];
            a0.x += s0*w.x; a0.y += s0*w.y; a0.z += s0*w.z; a0.w += s0*w.w;
            a1.x += s1*w.x; a1.y += s1*w.y; a1.z += s1*w.z; a1.w += s1*w.w;
            a2.x += s2*w.x; a2.y += s2*w.y; a2.z += s2*w.z; a2.w += s2*w.w;
            a3.x += s3*w.x; a3.y += s3*w.y; a3.z += s3*w.z; a3.w += s3*w.w;
            a4.x += s4*w.x; a4.y += s4*w.y; a4.z += s4*w.z; a4.w += s4*w.w;
            a5.x += s5*w.x; a5.y += s5*w.y; a5.z += s5*w.z; a5.w += s5*w.w;
        }
        *reinterpret_cast<float4*>(&pp[ksl][0][4*h4]) = a0;
        *reinterpret_cast<float4*>(&pp[ksl][1][4*h4]) = a1;
        *reinterpret_cast<float4*>(&pp[ksl][2][4*h4]) = a2;
        *reinterpret_cast<float4*>(&pp[ksl][3][4*h4]) = a3;
        *reinterpret_cast<float4*>(&pp[ksl][4][4*h4]) = a4;
        *reinterpret_cast<float4*>(&pp[ksl][5][4*h4]) = a5;
    }
    __syncthreads();
    for (int i = tid; i < 768; i += 512){
        int r = i >> 7, h = i & 127;
        float acc = bu[h];
        #pragma unroll
        for (int q = 0; q < 16; ++q) acc += pp[q][r][h];
        hid[(m0 + r) * HD + h] = acc;
        sH[r][h] = acc;
        sB[r][h] = acc;
        sB[r][128 + h] = sA[r][h];
        sC[r][64 + h] = acc;
    }
    __syncthreads();
    if (tid < 128){
        long long s = 0;
        #pragma unroll
        for (int r = 0; r < 6; ++r) s += llrintf(sH[r][tid] * 1048576.f);
        atomicAdd(&msbuf[(t & 1) * HD + tid], (unsigned long long)s);
    }

    {
        float4 a0 = make_float4(0,0,0,0), a1 = a0, a2 = a0, a3 = a0, a4 = a0, a5 = a0;
        #pragma unroll
        for (int kk = 0; kk < 8; ++kk){
            int k = ksl2 * 8 + kk;
            float4 w = Wd4[k * 16 + c4];
            float s0 = sB[0][k], s1 = sB[1][k], s2 = sB[2][k];
            float s3 = sB[3][k], s4 = sB[4][k], s5 = sB[5][k];
            a0.x += s0*w.x; a0.y += s0*w.y; a0.z += s0*w.z; a0.w += s0*w.w;
            a1.x += s1*w.x; a1.y += s1*w.y; a1.z += s1*w.z; a1.w += s1*w.w;
            a2.x += s2*w.x; a2.y += s2*w.y; a2.z += s2*w.z; a2.w += s2*w.w;
            a3.x += s3*w.x; a3.y += s3*w.y; a3.z += s3*w.z; a3.w += s3*w.w;
            a4.x += s4*w.x; a4.y += s4*w.y; a4.z += s4*w.z; a4.w += s4*w.w;
            a5.x += s5*w.x; a5.y += s5*w.y; a5.z += s5*w.z; a5.w += s5*w.w;
        }
        *reinterpret_cast<float4*>(&ppf[(ksl2*6 + 0)*64 + 4*c4]) = a0;
        *reinterpret_cast<float4*>(&ppf[(ksl2*6 + 1)*64 + 4*c4]) = a1;
        *reinterpret_cast<float4*>(&ppf[(ksl2*6 + 2)*64 + 4*c4]) = a2;
        *reinterpret_cast<float4*>(&ppf[(ksl2*6 + 3)*64 + 4*c4]) = a3;
        *reinterpret_cast<float4*>(&ppf[(ksl2*6 + 4)*64 + 4*c4]) = a4;
        *reinterpret_cast<float4*>(&ppf[(ksl2*6 + 5)*64 + 4*c4]) = a5;
    }
    __syncthreads();
    if (tid < 384){
        int r = tid >> 6, c = tid & 63;
        float acc = bd[c];
        #pragma unroll
        for (int q = 0; q < 32; ++q) acc += ppf[(q*6 + r)*64 + c];
        state[(m0 + r) * IND + c] = acc;
        out[(m0 + r) * 256 + (t + 1) * IND + c] = acc;
        sC[r][c] = acc;
    }
    __syncthreads();

    if (t < TT - 1){
        {
            float4 a0 = make_float4(0,0,0,0), a1 = a0, a2 = a0, a3 = a0, a4 = a0, a5 = a0;
            #pragma unroll
            for (int kk = 0; kk < 12; ++kk){
                int k = ksl * 12 + kk;
                float4 w = We4[k * 32 + h4];
                float s0 = sC[0][k], s1 = sC[1][k], s2 = sC[2][k];
                float s3 = sC[3][k], s4 = sC[4][k], s5 = sC[5][k];
                a0.x += s0*w.x; a0.y += s0*w.y; a0.z += s0*w.z; a0.w += s0*w.w;
                a1.x += s1*w.x; a1.y += s1*w.y; a1.z += s1*w.z; a1.w += s1*w.w;
                a2.x += s2*w.x; a2.y += s2*w.y; a2.z += s2*w.z; a2.w += s2*w.w;
                a3.x += s3*w.x; a3.y += s3*w.y; a3.z += s3*w.z; a3.w += s3*w.w;
                a4.x += s4*w.x; a4.y += s4*w.y; a4.z += s4*w.z; a4.w += s4*w.w;
                a5.x += s5*w.x; a5.y += s5*w.y; a5.z += s5*w.z; a5.w += s5*w.w;
            }
            *reinterpret_cast<float4*>(&pp[ksl][0][4*h4]) = a0;
            *reinterpret_cast<float4*>(&pp[ksl][1][4*h4]) = a1;
            *reinterpret_cast<float4*>(&pp[ksl][2][4*h4]) = a2;
            *reinterpret_cast<float4*>(&pp[ksl][3][4*h4]) = a3;
            *reinterpret_cast<float4*>(&pp[ksl][4][4*h4]) = a4;
            *reinterpret_cast<float4*>(&pp[ksl][5][4*h4]) = a5;
        }
        __syncthreads();
        for (int i = tid; i < 768; i += 512){
            int r = i >> 7, h = i & 127;
            float acc = be[h];
            #pragma unroll
            for (int q = 0; q < 16; ++q) acc += pp[q][r][h];
            z[(m0 + r) * HD + h] = acc;
            sZ2[r][h] = acc;
        }
        __syncthreads();

        float4 aS0 = make_float4(0,0,0,0), aS1 = aS0, aS2 = aS0, aS3 = aS0, aS4 = aS0, aS5 = aS0;
        float4 aD0 = aS0, aD1 = aS0, aD2 = aS0, aD3 = aS0, aD4 = aS0, aD5 = aS0;
        #pragma unroll
        for (int kk = 0; kk < 8; ++kk){
            int k = ksl * 8 + kk;
            float4 wS = WmS4[k * 32 + h4];
            float4 wD = WmD4[k * 32 + h4];
            float s0 = sZ2[0][k], s1 = sZ2[1][k], s2 = sZ2[2][k];
            float s3 = sZ2[3][k], s4 = sZ2[4][k], s5 = sZ2[5][k];
            aS0.x += s0*wS.x; aS0.y += s0*wS.y; aS0.z += s0*wS.z; aS0.w += s0*wS.w;
            aS1.x += s1*wS.x; aS1.y += s1*wS.y; aS1.z += s1*wS.z; aS1.w += s1*wS.w;
            aS2.x += s2*wS.x; aS2.y += s2*wS.y; aS2.z += s2*wS.z; aS2.w += s2*wS.w;
            aS3.x += s3*wS.x; aS3.y += s3*wS.y; aS3.z += s3*wS.z; aS3.w += s3*wS.w;
            aS4.x += s4*wS.x; aS4.y += s4*wS.y; aS4.z += s4*wS.z; aS4.w += s4*wS.w;
            aS5.x += s5*wS.x; aS5.y += s5*wS.y; aS5.z += s5*wS.z; aS5.w += s5*wS.w;
            aD0.x += s0*wD.x; aD0.y += s0*wD.y; aD0.z += s0*wD.z; aD0.w += s0*wD.w;
            aD1.x += s1*wD.x; aD1.y += s1*wD.y; aD1.z += s1*wD.z; aD1.w += s1*wD.w;
            aD2.x += s2*wD.x; aD2.y += s2*wD.y; aD2.z += s2*wD.z; aD2.w += s2*wD.w;
            aD3.x += s3*wD.x; aD3.y += s3*wD.y; aD3.z += s3*wD.z; aD3.w += s3*wD.w;
            aD4.x += s4*wD.x; aD4.y += s4*wD.y; aD4.z += s4*wD.z; aD4.w += s4*wD.w;
            aD5.x += s5*wD.x; aD5.y += s5*wD.y; aD5.z += s5*wD.z; aD5.w += s5*wD.w;
        }
        *reinterpret_cast<float4*>(&pp[ksl][0][4*h4]) = aS0;
        *reinterpret_cast<float4*>(&pp[ksl][1][4*h4]) = aS1;
        *reinterpret_cast<float4*>(&pp[ksl][2][4*h4]) = aS2;
        *reinterpret_cast<float4*>(&pp[ksl][3][4*h4]) = aS3;
        *reinterpret_cast<float4*>(&pp[ksl][4][4*h4]) = aS4;
        *reinterpret_cast<float4*>(&pp[ksl][5][4*h4]) = aS5;
        __syncthreads();
        for (int i = tid; i < 768; i += 512){
            int r = i >> 7, h = i & 127;
            float acc = 0.f;
            #pragma unroll
            for (int q = 0; q < 16; ++q) acc += pp[q][r][h];
            zsrc[(m0 + r) * HD + h] = acc;
        }
        __syncthreads();
        *reinterpret_cast<float4*>(&pp[ksl][0][4*h4]) = aD0;
        *reinterpret_cast<float4*>(&pp[ksl][1][4*h4]) = aD1;
        *reinterpret_cast<float4*>(&pp[ksl][2][4*h4]) = aD2;
        *reinterpret_cast<float4*>(&pp[ksl][3][4*h4]) = aD3;
        *reinterpret_cast<float4*>(&pp[ksl][4][4*h4]) = aD4;
        *reinterpret_cast<float4*>(&pp[ksl][5][4*h4]) = aD5;
        __syncthreads();
        for (int i = tid; i < 768; i += 512){
            int r = i >> 7, h = i & 127;
            float acc = 0.f;
            #pragma unroll
            for (int q = 0; q < 16; ++q) acc += pp[q][r][h];
            zdst[(m0 + r) * HD + h] = acc;
        }
    }
}

// ---------- final stop (t = TT-1) ----------
__global__ void kstop_ker(const float* __restrict__ hid, const unsigned long long* __restrict__ msbuf,
                          const float* __restrict__ Wt, const float* __restrict__ bt,
                          float* __restrict__ out)
{
    int tid = threadIdx.x;
    if (tid < 12){
        int row = blockIdx.x * 6 + (tid >> 1), cc = tid & 1;
        float a2 = bt[cc];
        const float* hrow = hid + row * HD;
        #pragma unroll 8
        for (int k = 0; k < HD; ++k) a2 += hrow[k] * Wt[k * 2 + cc];
        const unsigned long long* msp = msbuf + ((TT - 1) & 1) * HD;
        const float sc = 1.0f / (768.0f * 1048576.0f);
        #pragma unroll 8
        for (int k = 0; k < HD; ++k){
            float mk = (float)(long long)msp[k] * sc;
            a2 += mk * Wt[(HD + k) * 2 + cc];
        }
        out[196608 + row * 8 + TT * 2 + cc] = 1.f / (1.f + expf(-a2));
    }
}

extern "C" void kernel_launch(void* const* d_in, const int* in_sizes, int n_in,
                              void* d_out, int out_size, void* d_ws, size_t ws_size,
                              hipStream_t stream){
    const float* states = (const float*)d_in[0];
    const float* edges  = (const float*)d_in[1];
    const float* We = (const float*)d_in[2];
    const float* be = (const float*)d_in[3];
    const float* Wm = (const float*)d_in[4];
    const float* bm = (const float*)d_in[5];
    const float* Wu = (const float*)d_in[6];
    const float* bu = (const float*)d_in[7];
    const float* Wd = (const float*)d_in[8];
    const float* bd = (const float*)d_in[9];
    const float* Wt = (const float*)d_in[10];
    const float* bt = (const float*)d_in[11];
    float* out = (float*)d_out;

    float* ws = (float*)d_ws;
    float* z       = ws;                        // 98304
    float* zsrc    = ws + 98304;                // 98304
    float* zdst    = ws + 196608;               // 98304
    float* hid     = ws + 294912;               // 98304
    float* state   = ws + 393216;               // 49152
    unsigned long long* msbuf = (unsigned long long*)(ws + 442368); // 256 ull = 512 f
    unsigned* u_enc = (unsigned*)(ws + 442880); // 3*768*128 = 294912 u32

    k1_ker<<<768, 256, 0, stream>>>(states, We, be, Wm, out, z, zsrc, zdst, u_enc);
    for (int t = 0; t < TT; ++t){
        k2_ker<<<512, 256, 0, stream>>>(edges, zsrc, Wm, u_enc, hid, msbuf, Wt, bt, out, t);
        k3_ker<<<128, 512, 0, stream>>>(z, zsrc, zdst, u_enc, bm, Wu, bu, Wd, bd,
                                        We, be, Wm, hid, state, msbuf, out, t);
    }
    kstop_ker<<<128, 256, 0, stream>>>(hid, msbuf, Wt, bt, out);
}

// Round 22
// 109.711 us; speedup vs baseline: 1.0318x; 1.0318x over previous
//
#include <hip/hip_runtime.h>
#include <cstdint>
#include <cstddef>

#define NN  768
#define IND 64
#define HD  128
#define EFD 16
#define TT  3

typedef __attribute__((ext_vector_type(8)))  short short8;
typedef __attribute__((ext_vector_type(16))) float floatx16;

__device__ __forceinline__ unsigned f2bf(float f){
    unsigned u = __float_as_uint(f);
    return (u + 0x7FFFu + ((u >> 16) & 1u)) >> 16;
}
// monotonic uint encoding of float for atomicMax
__device__ __forceinline__ unsigned enc_f(float f){
    unsigned b = __float_as_uint(f);
    return (b & 0x80000000u) ? ~b : (b | 0x80000000u);
}
__device__ __forceinline__ float dec_f(unsigned e){
    return __uint_as_float((e & 0x80000000u) ? (e & 0x7FFFFFFFu) : ~e);
}
#define ENC_NEG_INF 0x007FFFFFu

// ---------- K1: z(0)+zsrc/zdst(0) row-local; edges f32->bf16; u_enc init; output init ----------
__global__ __launch_bounds__(256)
void k1_ker(const float* __restrict__ states, const float* __restrict__ edges,
            const float* __restrict__ We, const float* __restrict__ be,
            const float* __restrict__ Wm, float* __restrict__ out,
            float* __restrict__ z, float* __restrict__ zsrc, float* __restrict__ zdst,
            unsigned short* __restrict__ ebf, unsigned* __restrict__ u_enc)
{
    int bid = blockIdx.x, tid = threadIdx.x;
    __shared__ float sZ[HD];
    if (tid < HD){
        float acc = be[tid];
        const float* srow = states + bid * IND;
        #pragma unroll
        for (int k = 0; k < IND; ++k) acc += srow[k] * We[k * HD + tid];
        z[bid * HD + tid] = acc;
        sZ[tid] = acc;
    }
    __syncthreads();
    {
        int h = tid & 127, which = tid >> 7;
        const float* W = Wm + which * HD * HD;
        float acc = 0.f;
        #pragma unroll 8
        for (int k = 0; k < HD; ++k) acc += sZ[k] * W[k * HD + h];
        (which ? zdst : zsrc)[bid * HD + h] = acc;
    }
    // edges conv: 2359296 float4 over 768*256 threads = 12 iters
    const float4* ef4 = reinterpret_cast<const float4*>(edges);
    uint2* eb2 = reinterpret_cast<uint2*>(ebf);
    int gid0 = bid * 256 + tid;
    for (int it = 0; it < 12; ++it){
        int gid = gid0 + it * 196608;
        float4 v = ef4[gid];
        uint2 p;
        p.x = f2bf(v.x) | (f2bf(v.y) << 16);
        p.y = f2bf(v.z) | (f2bf(v.w) << 16);
        eb2[gid] = p;
    }
    // u_enc init: 3*768*128 = 294912 over 196608 threads
    u_enc[gid0] = ENC_NEG_INF;
    if (gid0 < 98304) u_enc[196608 + gid0] = ENC_NEG_INF;
    if (gid0 < NN * IND){ int n = gid0 >> 6, c = gid0 & 63; out[n * 256 + c] = states[n * IND + c]; }
    if (gid0 < NN * 2){ int n = gid0 >> 1, cc = gid0 & 1; out[196608 + n * 8 + cc] = 0.f; }
}

// ---------- K2 v3: MFMA msgmax, 4 h-tiles per wave (edges read once), LDS reduce, 1 atomic/elem ----------
// main blocks: (jt 0..23) x (ch 0..15) = 384 ; aux blocks 384..511: msbuf zero + stop(t-1)
__global__ __launch_bounds__(256)
void k2_ker(const unsigned short* __restrict__ ebf, const float* __restrict__ zsrc,
            const float* __restrict__ Wm, unsigned* __restrict__ u_enc,
            const float* __restrict__ hid, unsigned long long* __restrict__ msbuf,
            const float* __restrict__ Wt, const float* __restrict__ bt,
            float* __restrict__ out, int t)
{
    int bid = blockIdx.x, tid = threadIdx.x;
    if (bid < 384){
        __shared__ float sm[4][4096];      // 64 KB: [wave][ht*1024 + row*32 + col]
        const float* WmE = Wm + 2 * HD * HD;
        int lane = tid & 63;
        int wv = tid >> 6;
        int jt = bid % 24, ch = bid / 24;  // ch 0..15
        int j0 = jt * 32;
        int i0 = ch * 48 + wv * 12;        // 16 chunks x 4 waves x 12 i = 768
        int ln = lane & 31, lh = lane >> 5;

        short8 b[4];
        #pragma unroll
        for (int ht = 0; ht < 4; ++ht)
            #pragma unroll
            for (int q = 0; q < 8; ++q)
                b[ht][q] = (short)f2bf(WmE[(8 * lh + q) * HD + ht * 32 + ln]);

        floatx16 czero;
        floatx16 run[4];
        #pragma unroll
        for (int r = 0; r < 16; ++r) czero[r] = 0.f;
        #pragma unroll
        for (int ht = 0; ht < 4; ++ht)
            #pragma unroll
            for (int r = 0; r < 16; ++r) run[ht][r] = -INFINITY;

        const unsigned short* abase = ebf + (size_t)(j0 + ln) * EFD + 8 * lh;
        for (int ii = 0; ii < 12; ++ii){
            int i = i0 + ii;
            short8 a = *reinterpret_cast<const short8*>(abase + (size_t)i * NN * EFD);
            const float* zr = zsrc + i * HD + ln;
            float zs0 = zr[0], zs1 = zr[32], zs2 = zr[64], zs3 = zr[96];
            floatx16 d0 = __builtin_amdgcn_mfma_f32_32x32x16_bf16(a, b[0], czero, 0, 0, 0);
            #pragma unroll
            for (int r = 0; r < 16; ++r) run[0][r] = fmaxf(run[0][r], d0[r] + zs0);
            floatx16 d1 = __builtin_amdgcn_mfma_f32_32x32x16_bf16(a, b[1], czero, 0, 0, 0);
            #pragma unroll
            for (int r = 0; r < 16; ++r) run[1][r] = fmaxf(run[1][r], d1[r] + zs1);
            floatx16 d2 = __builtin_amdgcn_mfma_f32_32x32x16_bf16(a, b[2], czero, 0, 0, 0);
            #pragma unroll
            for (int r = 0; r < 16; ++r) run[2][r] = fmaxf(run[2][r], d2[r] + zs2);
            floatx16 d3 = __builtin_amdgcn_mfma_f32_32x32x16_bf16(a, b[3], czero, 0, 0, 0);
            #pragma unroll
            for (int r = 0; r < 16; ++r) run[3][r] = fmaxf(run[3][r], d3[r] + zs3);
        }
        // per-wave maxes -> LDS
        #pragma unroll
        for (int ht = 0; ht < 4; ++ht)
            #pragma unroll
            for (int r = 0; r < 16; ++r){
                int row = (r & 3) + 8 * (r >> 2) + 4 * lh;
                sm[wv][ht * 1024 + row * 32 + ln] = run[ht][r];
            }
        __syncthreads();
        // 4-wave reduce + single atomic per element per block
        unsigned* ub = u_enc + t * (NN * HD);
        #pragma unroll
        for (int e = tid; e < 4096; e += 256){
            float m = fmaxf(fmaxf(sm[0][e], sm[1][e]), fmaxf(sm[2][e], sm[3][e]));
            int ht = e >> 10, rr = e & 1023;
            int jr = rr >> 5, hc = rr & 31;
            atomicMax(&ub[(j0 + jr) * HD + ht * 32 + hc], enc_f(m));
        }
    } else {
        int b2 = bid - 384;
        if (b2 == 0 && tid < HD) msbuf[(t & 1) * HD + tid] = 0ull;
        if (t > 0 && tid < 12){
            int row = b2 * 6 + (tid >> 1), cc = tid & 1;
            float a2 = bt[cc];
            const float* hrow = hid + row * HD;
            #pragma unroll 8
            for (int k = 0; k < HD; ++k) a2 += hrow[k] * Wt[k * 2 + cc];
            const unsigned long long* msp = msbuf + ((t - 1) & 1) * HD;
            const float sc = 1.0f / (768.0f * 1048576.0f);
            #pragma unroll 8
            for (int k = 0; k < HD; ++k){
                float mk = (float)(long long)msp[k] * sc;
                a2 += mk * Wt[(HD + k) * 2 + cc];
            }
            out[196608 + row * 8 + t * 2 + cc] = 1.f / (1.f + expf(-a2));
        }
    }
}

// ---------- K3 v5: 6 rows/block, 128 blocks, 512 threads; weight float4 loaded once, reused x6 rows ----------
__global__ __launch_bounds__(512)
void k3_ker(float* __restrict__ z, float* __restrict__ zsrc, float* __restrict__ zdst,
            const unsigned* __restrict__ u_enc, const float* __restrict__ bm,
            const float* __restrict__ Wu, const float* __restrict__ bu,
            const float* __restrict__ Wd, const float* __restrict__ bd,
            const float* __restrict__ We, const float* __restrict__ be,
            const float* __restrict__ Wm,
            float* __restrict__ hid, float* __restrict__ state,
            unsigned long long* __restrict__ msbuf, float* __restrict__ out, int t)
{
    __shared__ float sA[6][256];
    __shared__ float sB[6][256];
    __shared__ float sC[6][192];
    __shared__ float sH[6][128];
    __shared__ float sZ2[6][128];
    __shared__ float pp[16][6][128];

    int tid = threadIdx.x;
    int m0 = blockIdx.x * 6;

    const float4* Wu4  = reinterpret_cast<const float4*>(Wu);
    const float4* Wd4  = reinterpret_cast<const float4*>(Wd);
    const float4* We4  = reinterpret_cast<const float4*>(We);
    const float4* WmS4 = reinterpret_cast<const float4*>(Wm);
    const float4* WmD4 = reinterpret_cast<const float4*>(Wm + HD * HD);
    float* ppf = &pp[0][0][0];

    for (int i = tid; i < 1536; i += 512){
        int r = i >> 8, k = i & 255;
        float v;
        if (k < HD) v = z[(m0 + r) * HD + k];
        else {
            int kk = k - HD;
            v = dec_f(u_enc[t * (NN * HD) + (m0 + r) * HD + kk]) + zdst[(m0 + r) * HD + kk] + bm[kk];
        }
        sA[r][k] = v;
    }
    __syncthreads();

    int h4 = tid & 31, ksl = tid >> 5;
    int c4 = tid & 15, ksl2 = tid >> 4;

    {
        float4 a0 = make_float4(0,0,0,0), a1 = a0, a2 = a0, a3 = a0, a4 = a0, a5 = a0;
        #pragma unroll
        for (int kk = 0; kk < 16; ++kk){
            int k = ksl * 16 + kk;
            float4 w = Wu4[k * 32 + h4];
            float s0 = sA[0][k], s1 = sA[1][k], s2 = sA[2][k];
            float s3 = sA[3][k], s4 = sA[4][k], s5 = sA[5][k];
            a0.x += s0*w.x; a0.y += s0*w.y; a0.z += s0*w.z; a0.w += s0*w.w;
            a1.x += s1*w.x; a1.y += s1*w.y; a1.z += s1*w.z; a1.w += s1*w.w;
            a2.x += s2*w.x; a2.y += s2*w.y; a2.z += s2*w.z; a2.w += s2*w.w;
            a3.x += s3*w.x; a3.y += s3*w.y; a3.z += s3*w.z; a3.w += s3*w.w;
            a4.x += s4*w.x; a4.y += s4*w.y; a4.z += s4*w.z; a4.w += s4*w.w;
            a5.x += s5*w.x; a5.y += s5*w.y; a5.z += s5*w.z; a5.w += s5*w.w;
        }
        *reinterpret_cast<float4*>(&pp[ksl][0][4*h4]) = a0;
        *reinterpret_cast<float4*>(&pp[ksl][1][4*h4]) = a1;
        *reinterpret_cast<float4*>(&pp[ksl][2][4*h4]) = a2;
        *reinterpret_cast<float4*>(&pp[ksl][3][4*h4]) = a3;
        *reinterpret_cast<float4*>(&pp[ksl][4][4*h4]) = a4;
        *reinterpret_cast<float4*>(&pp[ksl][5][4*h4]) = a5;
    }
    __syncthreads();
    for (int i = tid; i < 768; i += 512){
        int r = i >> 7, h = i & 127;
        float acc = bu[h];
        #pragma unroll
        for (int q = 0; q < 16; ++q) acc += pp[q][r][h];
        hid[(m0 + r) * HD + h] = acc;
        sH[r][h] = acc;
        sB[r][h] = acc;
        sB[r][128 + h] = sA[r][h];
        sC[r][64 + h] = acc;
    }
    __syncthreads();
    if (tid < 128){
        long long s = 0;
        #pragma unroll
        for (int r = 0; r < 6; ++r) s += llrintf(sH[r][tid] * 1048576.f);
        atomicAdd(&msbuf[(t & 1) * HD + tid], (unsigned long long)s);
    }

    {
        float4 a0 = make_float4(0,0,0,0), a1 = a0, a2 = a0, a3 = a0, a4 = a0, a5 = a0;
        #pragma unroll
        for (int kk = 0; kk < 8; ++kk){
            int k = ksl2 * 8 + kk;
            float4 w = Wd4[k * 16 + c4];
            float s0 = sB[0][k], s1 = sB[1][k], s2 = sB[2][k];
            float s3 = sB[3][k], s4 = sB[4][k], s5 = sB[5][k];
            a0.x += s0*w.x; a0.y += s0*w.y; a0.z += s0*w.z; a0.w += s0*w.w;
            a1.x += s1*w.x; a1.y += s1*w.y; a1.z += s1*w.z; a1.w += s1*w.w;
            a2.x += s2*w.x; a2.y += s2*w.y; a2.z += s2*w.z; a2.w += s2*w.w;
            a3.x += s3*w.x; a3.y += s3*w.y; a3.z += s3*w.z; a3.w += s3*w.w;
            a4.x += s4*w.x; a4.y += s4*w.y; a4.z += s4*w.z; a4.w += s4*w.w;
            a5.x += s5*w.x; a5.y += s5*w.y; a5.z += s5*w.z; a5.w += s5*w.w;
        }
        *reinterpret_cast<float4*>(&ppf[(ksl2*6 + 0)*64 + 4*c4]) = a0;
        *reinterpret_cast<float4*>(&ppf[(ksl2*6 + 1)*64 + 4*c4]) = a1;
        *reinterpret_cast<float4*>(&ppf[(ksl2*6 + 2)*64 + 4*c4]) = a2;
        *reinterpret_cast<float4*>(&ppf[(ksl2*6 + 3)*64 + 4*c4]) = a3;
        *reinterpret_cast<float4*>(&ppf[(ksl2*6 + 4)*64 + 4*c4]) = a4;
        *reinterpret_cast<float4*>(&ppf[(ksl2*6 + 5)*64 + 4*c4]) = a5;
    }
    __syncthreads();
    if (tid < 384){
        int r = tid >> 6, c = tid & 63;
        float acc = bd[c];
        #pragma unroll
        for (int q = 0; q < 32; ++q) acc += ppf[(q*6 + r)*64 + c];
        state[(m0 + r) * IND + c] = acc;
        out[(m0 + r) * 256 + (t + 1) * IND + c] = acc;
        sC[r][c] = acc;
    }
    __syncthreads();

    if (t < TT - 1){
        {
            float4 a0 = make_float4(0,0,0,0), a1 = a0, a2 = a0, a3 = a0, a4 = a0, a5 = a0;
            #pragma unroll
            for (int kk = 0; kk < 12; ++kk){
                int k = ksl * 12 + kk;
                float4 w = We4[k * 32 + h4];
                float s0 = sC[0][k], s1 = sC[1][k], s2 = sC[2][k];
                float s3 = sC[3][k], s4 = sC[4][k], s5 = sC[5][k];
                a0.x += s0*w.x; a0.y += s0*w.y; a0.z += s0*w.z; a0.w += s0*w.w;
                a1.x += s1*w.x; a1.y += s1*w.y; a1.z += s1*w.z; a1.w += s1*w.w;
                a2.x += s2*w.x; a2.y += s2*w.y; a2.z += s2*w.z; a2.w += s2*w.w;
                a3.x += s3*w.x; a3.y += s3*w.y; a3.z += s3*w.z; a3.w += s3*w.w;
                a4.x += s4*w.x; a4.y += s4*w.y; a4.z += s4*w.z; a4.w += s4*w.w;
                a5.x += s5*w.x; a5.y += s5*w.y; a5.z += s5*w.z; a5.w += s5*w.w;
            }
            *reinterpret_cast<float4*>(&pp[ksl][0][4*h4]) = a0;
            *reinterpret_cast<float4*>(&pp[ksl][1][4*h4]) = a1;
            *reinterpret_cast<float4*>(&pp[ksl][2][4*h4]) = a2;
            *reinterpret_cast<float4*>(&pp[ksl][3][4*h4]) = a3;
            *reinterpret_cast<float4*>(&pp[ksl][4][4*h4]) = a4;
            *reinterpret_cast<float4*>(&pp[ksl][5][4*h4]) = a5;
        }
        __syncthreads();
        for (int i = tid; i < 768; i += 512){
            int r = i >> 7, h = i & 127;
            float acc = be[h];
            #pragma unroll
            for (int q = 0; q < 16; ++q) acc += pp[q][r][h];
            z[(m0 + r) * HD + h] = acc;
            sZ2[r][h] = acc;
        }
        __syncthreads();

        float4 aS0 = make_float4(0,0,0,0), aS1 = aS0, aS2 = aS0, aS3 = aS0, aS4 = aS0, aS5 = aS0;
        float4 aD0 = aS0, aD1 = aS0, aD2 = aS0, aD3 = aS0, aD4 = aS0, aD5 = aS0;
        #pragma unroll
        for (int kk = 0; kk < 8; ++kk){
            int k = ksl * 8 + kk;
            float4 wS = WmS4[k * 32 + h4];
            float4 wD = WmD4[k * 32 + h4];
            float s0 = sZ2[0][k], s1 = sZ2[1][k], s2 = sZ2[2][k];
            float s3 = sZ2[3][k], s4 = sZ2[4][k], s5 = sZ2[5][k];
            aS0.x += s0*wS.x; aS0.y += s0*wS.y; aS0.z += s0*wS.z; aS0.w += s0*wS.w;
            aS1.x += s1*wS.x; aS1.y += s1*wS.y; aS1.z += s1*wS.z; aS1.w += s1*wS.w;
            aS2.x += s2*wS.x; aS2.y += s2*wS.y; aS2.z += s2*wS.z; aS2.w += s2*wS.w;
            aS3.x += s3*wS.x; aS3.y += s3*wS.y; aS3.z += s3*wS.z; aS3.w += s3*wS.w;
            aS4.x += s4*wS.x; aS4.y += s4*wS.y; aS4.z += s4*wS.z; aS4.w += s4*wS.w;
            aS5.x += s5*wS.x; aS5.y += s5*wS.y; aS5.z += s5*wS.z; aS5.w += s5*wS.w;
            aD0.x += s0*wD.x; aD0.y += s0*wD.y; aD0.z += s0*wD.z; aD0.w += s0*wD.w;
            aD1.x += s1*wD.x; aD1.y += s1*wD.y; aD1.z += s1*wD.z; aD1.w += s1*wD.w;
            aD2.x += s2*wD.x; aD2.y += s2*wD.y; aD2.z += s2*wD.z; aD2.w += s2*wD.w;
            aD3.x += s3*wD.x; aD3.y += s3*wD.y; aD3.z += s3*wD.z; aD3.w += s3*wD.w;
            aD4.x += s4*wD.x; aD4.y += s4*wD.y; aD4.z += s4*wD.z; aD4.w += s4*wD.w;
            aD5.x += s5*wD.x; aD5.y += s5*wD.y; aD5.z += s5*wD.z; aD5.w += s5*wD.w;
        }
        *reinterpret_cast<float4*>(&pp[ksl][0][4*h4]) = aS0;
        *reinterpret_cast<float4*>(&pp[ksl][1][4*h4]) = aS1;
        *reinterpret_cast<float4*>(&pp[ksl][2][4*h4]) = aS2;
        *reinterpret_cast<float4*>(&pp[ksl][3][4*h4]) = aS3;
        *reinterpret_cast<float4*>(&pp[ksl][4][4*h4]) = aS4;
        *reinterpret_cast<float4*>(&pp[ksl][5][4*h4]) = aS5;
        __syncthreads();
        for (int i = tid; i < 768; i += 512){
            int r = i >> 7, h = i & 127;
            float acc = 0.f;
            #pragma unroll
            for (int q = 0; q < 16; ++q) acc += pp[q][r][h];
            zsrc[(m0 + r) * HD + h] = acc;
        }
        __syncthreads();
        *reinterpret_cast<float4*>(&pp[ksl][0][4*h4]) = aD0;
        *reinterpret_cast<float4*>(&pp[ksl][1][4*h4]) = aD1;
        *reinterpret_cast<float4*>(&pp[ksl][2][4*h4]) = aD2;
        *reinterpret_cast<float4*>(&pp[ksl][3][4*h4]) = aD3;
        *reinterpret_cast<float4*>(&pp[ksl][4][4*h4]) = aD4;
        *reinterpret_cast<float4*>(&pp[ksl][5][4*h4]) = aD5;
        __syncthreads();
        for (int i = tid; i < 768; i += 512){
            int r = i >> 7, h = i & 127;
            float acc = 0.f;
            #pragma unroll
            for (int q = 0; q < 16; ++q) acc += pp[q][r][h];
            zdst[(m0 + r) * HD + h] = acc;
        }
    }
}

// ---------- final stop (t = TT-1) ----------
__global__ void kstop_ker(const float* __restrict__ hid, const unsigned long long* __restrict__ msbuf,
                          const float* __restrict__ Wt, const float* __restrict__ bt,
                          float* __restrict__ out)
{
    int tid = threadIdx.x;
    if (tid < 12){
        int row = blockIdx.x * 6 + (tid >> 1), cc = tid & 1;
        float a2 = bt[cc];
        const float* hrow = hid + row * HD;
        #pragma unroll 8
        for (int k = 0; k < HD; ++k) a2 += hrow[k] * Wt[k * 2 + cc];
        const unsigned long long* msp = msbuf + ((TT - 1) & 1) * HD;
        const float sc = 1.0f / (768.0f * 1048576.0f);
        #pragma unroll 8
        for (int k = 0; k < HD; ++k){
            float mk = (float)(long long)msp[k] * sc;
            a2 += mk * Wt[(HD + k) * 2 + cc];
        }
        out[196608 + row * 8 + TT * 2 + cc] = 1.f / (1.f + expf(-a2));
    }
}

extern "C" void kernel_launch(void* const* d_in, const int* in_sizes, int n_in,
                              void* d_out, int out_size, void* d_ws, size_t ws_size,
                              hipStream_t stream){
    const float* states = (const float*)d_in[0];
    const float* edges  = (const float*)d_in[1];
    const float* We = (const float*)d_in[2];
    const float* be = (const float*)d_in[3];
    const float* Wm = (const float*)d_in[4];
    const float* bm = (const float*)d_in[5];
    const float* Wu = (const float*)d_in[6];
    const float* bu = (const float*)d_in[7];
    const float* Wd = (const float*)d_in[8];
    const float* bd = (const float*)d_in[9];
    const float* Wt = (const float*)d_in[10];
    const float* bt = (const float*)d_in[11];
    float* out = (float*)d_out;

    float* ws = (float*)d_ws;
    float* z       = ws;                        // 98304
    float* zsrc    = ws + 98304;                // 98304
    float* zdst    = ws + 196608;               // 98304
    float* hid     = ws + 294912;               // 98304
    float* state   = ws + 393216;               // 49152
    unsigned long long* msbuf = (unsigned long long*)(ws + 442368); // 256 ull = 512 f
    unsigned* u_enc = (unsigned*)(ws + 442880); // 3*768*128 = 294912 u32
    unsigned short* ebf = (unsigned short*)(ws + 737792); // 9437184 bf16

    k1_ker<<<768, 256, 0, stream>>>(states, edges, We, be, Wm, out, z, zsrc, zdst, ebf, u_enc);
    for (int t = 0; t < TT; ++t){
        k2_ker<<<512, 256, 0, stream>>>(ebf, zsrc, Wm, u_enc, hid, msbuf, Wt, bt, out, t);
        k3_ker<<<128, 512, 0, stream>>>(z, zsrc, zdst, u_enc, bm, Wu, bu, Wd, bd,
                                        We, be, Wm, hid, state, msbuf, out, t);
    }
    kstop_ker<<<128, 256, 0, stream>>>(hid, msbuf, Wt, bt, out);
}